// Round 1
// baseline (128.715 us; speedup 1.0000x reference)
//
#include <hip/hip_runtime.h>

// NonZeroFeatureExtractor — fused multi-scale box features, wide tiles.
// 256-thread block = 223 output cols x 64 output rows. Per iteration (2 rows):
// prefetch 2x3 global loads -> DPP wave scan (VALU) + ballot/mbcnt nz prefix
// -> ONE barrier -> {cross-wave offset + ring write of rows yk+16/17} fused
// with {vertical slide + emit of rows yk-2/yk-1} (delayed emit: consume phase
// only reads rows written in PREVIOUS iterations, so write/read slots are
// disjoint and the second barrier is gone; RING=38 gives 1 slot WAR slack,
// wsum is parity-double-buffered against lagging waves).
// Divisions use v_rcp_f32 (tolerance 3.9e-3 abs >> 1e-6 rcp error).
// Barriers drain lgkmcnt only; global prefetches stay in flight across them.

constexpr int THREADS = 256;
constexpr int LOADW   = 256;
constexpr int HALO    = 17;
constexpr int COUT    = 223;   // LOADW - 33
constexpr int RING    = 38;    // live span per phase: 37 rows + 1 slack
constexpr int ROWSEG  = 64;

__device__ __forceinline__ void barrier_lds() {
    asm volatile("s_waitcnt lgkmcnt(0)" ::: "memory");
    __builtin_amdgcn_s_barrier();
    __builtin_amdgcn_sched_barrier(0);
}

template<int CTRL, int RM>
__device__ __forceinline__ float dppadd(float v) {
    int sh = __builtin_amdgcn_update_dpp(0, __float_as_int(v), CTRL, RM, 0xF, true);
    return v + __int_as_float(sh);
}

// 64-lane inclusive scan, pure VALU (validated round 3 of prior session)
__device__ __forceinline__ float wave_iscan(float v) {
    v = dppadd<0x111, 0xF>(v);   // row_shr:1
    v = dppadd<0x112, 0xF>(v);   // row_shr:2
    v = dppadd<0x114, 0xF>(v);   // row_shr:4
    v = dppadd<0x118, 0xF>(v);   // row_shr:8
    v = dppadd<0x142, 0xA>(v);   // ROW_BCAST15 -> rows 1,3
    v = dppadd<0x143, 0xC>(v);   // ROW_BCAST31 -> rows 2,3
    return v;
}

__global__ __launch_bounds__(THREADS, 3)
void nzfeat_kernel(const float* __restrict__ x, float* __restrict__ out,
                   int B, int H, int W) {
    constexpr int   PP[4]   = {1, 4, 8, 16};
    constexpr float INVA[4] = {1.f/9.f, 1.f/81.f, 1.f/289.f, 1.f/1089.f};

    __shared__ float         ringL[RING][LOADW];   // global lum prefix
    __shared__ unsigned char ringN[RING][LOADW];   // global nz prefix mod 256
    __shared__ float2        wsum[2][2][4];        // [iter parity][row][wave]

    const int t    = threadIdx.x;
    const int lane = t & 63;
    const int wv   = t >> 6;

    const int x0 = blockIdx.x * COUT;
    const int y0 = blockIdx.y * ROWSEG;
    const int b  = blockIdx.z;

    const int    gx   = x0 - HALO + t;
    const bool   gxok = (gx >= 0) && (gx < W);
    const int    gxc  = min(max(gx, 0), W - 1);
    const size_t HW   = (size_t)H * W;
    const float* xb   = x + (size_t)b * 3 * HW + gxc;

    auto load_row = [&](int r, float& a0, float& a1, float& a2) {
        const int rc = min(max(r, 0), H - 1);
        const float* p = xb + (size_t)rc * W;
        a0 = p[0]; a1 = p[HW]; a2 = p[2 * HW];
    };

    auto slotOf = [&](int r) { return (int)((unsigned)(r + 2 * RING) % (unsigned)RING); };
    auto wpos   = [&](int v) { return v >= RING ? v - RING : v; };
    auto wneg   = [&](int v) { return v < 0 ? v + RING : v; };

    // local (per-wave-segment) inclusive prefixes; lane 63 posts wave totals
    auto scan_local = [&](float c0, float c1, float c2, int r, int par, int which) -> float2 {
        float lum = 0.f;
        if (gxok && (unsigned)r < (unsigned)H)
            lum = (c0 + c1 + c2) * (1.0f / 3.0f);
        const bool nzb = (lum != 0.f);
        unsigned long long m = __ballot(nzb);
        int below = __builtin_amdgcn_mbcnt_hi((unsigned)(m >> 32),
                      __builtin_amdgcn_mbcnt_lo((unsigned)m, 0));
        float np = (float)below + (nzb ? 1.f : 0.f);
        float lp = wave_iscan(lum);
        if (lane == 63) wsum[par][which][wv] = make_float2(lp, np);
        return make_float2(lp, np);
    };

    // add lower-wave totals, write global prefixes to ring
    auto combine_write = [&](int par, float2 A, float2 Bv, int sA, int sB) {
        float oAl = 0.f, oAn = 0.f, oBl = 0.f, oBn = 0.f;
        #pragma unroll
        for (int w2 = 0; w2 < 3; ++w2)
            if (w2 < wv) {
                float2 u = wsum[par][0][w2]; float2 v = wsum[par][1][w2];
                oAl += u.x; oAn += u.y; oBl += v.x; oBn += v.y;
            }
        ringL[sA][t] = A.x + oAl;
        ringN[sA][t] = (unsigned char)(int)(A.y + oAn);
        ringL[sB][t] = Bv.x + oBl;
        ringN[sB][t] = (unsigned char)(int)(Bv.y + oBn);
    };

    // ---- prologue: scan rows [y0-18, y0+15], ONE barrier per pair ----
    // (WAR on wsum across iterations is handled by the parity buffer; ring
    //  writes go to 34 distinct slots < RING, so no ring hazard here.)
    float a0, a1, a2, b0c, b1c, b2c;
    load_row(y0 - 18, a0, a1, a2);
    load_row(y0 - 17, b0c, b1c, b2c);
    for (int i = 0; i < 17; ++i) {
        const int rA = y0 - 18 + 2 * i;
        float n0, n1, n2, m0, m1, m2;
        load_row(rA + 2, n0, n1, n2);
        load_row(rA + 3, m0, m1, m2);
        float2 A  = scan_local(a0, a1, a2, rA, i & 1, 0);
        float2 Bv = scan_local(b0c, b1c, b2c, rA + 1, i & 1, 1);
        barrier_lds();
        combine_write(i & 1, A, Bv, slotOf(rA), slotOf(rA + 1));
        a0 = n0; a1 = n1; a2 = n2; b0c = m0; b1c = m1; b2c = m2;
    }
    // regs now hold rows y0+16, y0+17
    barrier_lds();   // last prologue writes visible before priming reads

    const bool activeCol = (t < COUT) && (x0 + t < W);
    float* outb = out + (size_t)b * 8 * HW + (x0 + t);

    // ---- prime vertical sums for virtual row y0-1 (reads rows y0-17..y0+15) ----
    float vl[4], vn[4];
    #pragma unroll
    for (int i = 0; i < 4; ++i) {
        const int p  = PP[i];
        const int d  = 2 * p + 1;
        const int x1 = t + HALO - p - 1;
        float sl = 0.f, sn = 0.f;
        for (int rr = y0 - 1 - p; rr <= y0 - 1 + p; ++rr) {
            const int s = slotOf(rr);
            sl += ringL[s][x1 + d] - ringL[s][x1];
            sn += (float)(unsigned char)(ringN[s][x1 + d] - ringN[s][x1]);
        }
        vl[i] = sl; vn[i] = sn;
    }

    // ---- main: k=0 scan-only; k=1..31 scan rows yk+16/17 AND emit rows
    //      yk-2/yk-1 (written <= previous iteration -> disjoint from this
    //      iteration's ring writes); k=32 emit-only drain. ONE barrier/iter.
    int sy = slotOf(y0);        // slot cursor for emitted rows
    int sw = slotOf(y0 + 16);   // slot cursor for written rows
    for (int k = 0; k <= ROWSEG / 2; ++k) {
        const bool doScan = (k < ROWSEG / 2);
        float2 A = make_float2(0.f, 0.f), Bv = make_float2(0.f, 0.f);
        float n0 = 0.f, n1 = 0.f, n2 = 0.f, m0 = 0.f, m1 = 0.f, m2 = 0.f;
        if (doScan) {
            const int wA = y0 + 2 * k + 16;
            if (k < ROWSEG / 2 - 1) {
                load_row(wA + 2, n0, n1, n2);
                load_row(wA + 3, m0, m1, m2);
            }
            A  = scan_local(a0, a1, a2, wA, k & 1, 0);
            Bv = scan_local(b0c, b1c, b2c, wA + 1, k & 1, 1);
        }
        barrier_lds();
        if (doScan) {
            combine_write(k & 1, A, Bv, sw, wpos(sw + 1));
            sw = wpos(sw + 2);
        }
        if (k >= 1) {
            const int ye = y0 + 2 * (k - 1);

            // slide to row ye, emit
            #pragma unroll
            for (int i = 0; i < 4; ++i) {
                const int p  = PP[i];
                const int d  = 2 * p + 1;
                const int x1 = t + HALO - p - 1;
                const int sE = wpos(sy + p);
                const int sL = wneg(sy - 1 - p);
                const float hlE = ringL[sE][x1 + d] - ringL[sE][x1];
                const float hnE = (float)(unsigned char)(ringN[sE][x1 + d] - ringN[sE][x1]);
                const float hlL = ringL[sL][x1 + d] - ringL[sL][x1];
                const float hnL = (float)(unsigned char)(ringN[sL][x1 + d] - ringN[sL][x1]);
                vl[i] += hlE - hlL;
                vn[i] += hnE - hnL;
            }
            if (activeCol && ye < H) {
                float* o = outb + (size_t)ye * W;
                #pragma unroll
                for (int i = 0; i < 4; ++i) {
                    o[(size_t)(2 * i) * HW]     = vn[i] * INVA[i];
                    o[(size_t)(2 * i + 1) * HW] =
                        vl[i] * __builtin_amdgcn_rcpf(fmaxf(vn[i], 1.f));
                }
            }

            // slide to row ye+1, emit
            #pragma unroll
            for (int i = 0; i < 4; ++i) {
                const int p  = PP[i];
                const int d  = 2 * p + 1;
                const int x1 = t + HALO - p - 1;
                const int sE = wpos(sy + p + 1);
                const int sL = wneg(sy - p);
                const float hlE = ringL[sE][x1 + d] - ringL[sE][x1];
                const float hnE = (float)(unsigned char)(ringN[sE][x1 + d] - ringN[sE][x1]);
                const float hlL = ringL[sL][x1 + d] - ringL[sL][x1];
                const float hnL = (float)(unsigned char)(ringN[sL][x1 + d] - ringN[sL][x1]);
                vl[i] += hlE - hlL;
                vn[i] += hnE - hnL;
            }
            if (activeCol && ye + 1 < H) {
                float* o = outb + (size_t)(ye + 1) * W;
                #pragma unroll
                for (int i = 0; i < 4; ++i) {
                    o[(size_t)(2 * i) * HW]     = vn[i] * INVA[i];
                    o[(size_t)(2 * i + 1) * HW] =
                        vl[i] * __builtin_amdgcn_rcpf(fmaxf(vn[i], 1.f));
                }
            }

            sy = wpos(sy + 2);
        }
        if (k < ROWSEG / 2 - 1) {
            a0 = n0; a1 = n1; a2 = n2; b0c = m0; b1c = m1; b2c = m2;
        }
    }
}

extern "C" void kernel_launch(void* const* d_in, const int* in_sizes, int n_in,
                              void* d_out, int out_size, void* d_ws, size_t ws_size,
                              hipStream_t stream) {
    const float* x   = (const float*)d_in[0];
    float*       out = (float*)d_out;

    const int H = 1024, W = 1024;
    const int B = in_sizes[0] / (3 * H * W);

    dim3 grid((W + COUT - 1) / COUT, (H + ROWSEG - 1) / ROWSEG, B);
    nzfeat_kernel<<<grid, dim3(THREADS), 0, stream>>>(x, out, B, H, W);
}